// Round 1
// baseline (1997.878 us; speedup 1.0000x reference)
//
#include <hip/hip_runtime.h>

#define NB 2048
#define NT 512
#define NF 64
#define NH 20
#define NG 80
#define TC 16
#define NCHUNK (NT/TC)   // 32
#define BPB 4
#define NBLK (NB/BPB)    // 512 blocks = exactly 2 per CU
#define PSTR 85          // p_s row stride (21 mod 32 -> conflict-free-ish)

__device__ __forceinline__ float sigm(float v)   { return 1.0f / (1.0f + __expf(-v)); }
__device__ __forceinline__ float tanh_f(float v) { return 1.0f - 2.0f / (1.0f + __expf(2.0f * v)); }

// Opaque register barrier: pin value in VGPRs, stop rematerialization.
#define OPAQ4(v) asm volatile("" : "+v"(v.x), "+v"(v.y), "+v"(v.z), "+v"(v.w))

// 4 h-broadcasts + 16 FMAs, split accumulators to halve the dep chain
#define K4(VWI, VWF, VWG, VWO, KB)                                            \
    {                                                                         \
        float hk0 = __shfl(ht, base + (KB) + 0, 64);                          \
        float hk1 = __shfl(ht, base + (KB) + 1, 64);                          \
        float hk2 = __shfl(ht, base + (KB) + 2, 64);                          \
        float hk3 = __shfl(ht, base + (KB) + 3, 64);                          \
        s0a = fmaf(VWI.x, hk0, s0a); s0b = fmaf(VWI.y, hk1, s0b);             \
        s0a = fmaf(VWI.z, hk2, s0a); s0b = fmaf(VWI.w, hk3, s0b);             \
        s1a = fmaf(VWF.x, hk0, s1a); s1b = fmaf(VWF.y, hk1, s1b);             \
        s1a = fmaf(VWF.z, hk2, s1a); s1b = fmaf(VWF.w, hk3, s1b);             \
        s2a = fmaf(VWG.x, hk0, s2a); s2b = fmaf(VWG.y, hk1, s2b);             \
        s2a = fmaf(VWG.z, hk2, s2a); s2b = fmaf(VWG.w, hk3, s2b);             \
        s3a = fmaf(VWO.x, hk0, s3a); s3b = fmaf(VWO.y, hk1, s3b);             \
        s3a = fmaf(VWO.z, hk2, s3a); s3b = fmaf(VWO.w, hk3, s3b);             \
    }

#define TSTEP(TL)                                                             \
    {                                                                         \
        const float* pr = pc + (TL) * PSTR;                                   \
        float s0a = pr[j]      + bias_i, s0b = 0.f;                           \
        float s1a = pr[j + 20] + bias_f, s1b = 0.f;                           \
        float s2a = pr[j + 40] + bias_g, s2b = 0.f;                           \
        float s3a = pr[j + 60] + bias_o, s3b = 0.f;                           \
        K4(wi0, wf0, wg0, wo0, 0)  K4(wi1, wf1, wg1, wo1, 4)                  \
        K4(wi2, wf2, wg2, wo2, 8)  K4(wi3, wf3, wg3, wo3, 12)                 \
        K4(wi4, wf4, wg4, wo4, 16)                                            \
        float gi = sigm(s0a + s0b);                                           \
        float gf = sigm(s1a + s1b);                                           \
        float gg = tanh_f(s2a + s2b);                                         \
        float go = sigm(s3a + s3b);                                           \
        creg = gf * creg + gi * gg;                                           \
        ht   = go * tanh_f(creg);                                             \
        accum = fmaf(ht, wlp[(TL) * NH], accum);                              \
    }

#define GFMA(AV, WV) { AV = fmaf(xv.x, WV.x, AV); AV = fmaf(xv.y, WV.y, AV);  \
                       AV = fmaf(xv.z, WV.z, AV); AV = fmaf(xv.w, WV.w, AV); }

__global__ __launch_bounds__(256, 2) void mv_lstm_fused(
    const float* __restrict__ x, const float* __restrict__ W_ih,
    const float* __restrict__ W_hh, const float* __restrict__ b_ih,
    const float* __restrict__ b_hh, const float* __restrict__ W_lin,
    const float* __restrict__ b_lin, float* __restrict__ out)
{
    __shared__ float p_s[2][BPB*TC][PSTR];   // 43.5 KB, only LDS in the kernel

    const int tid  = threadIdx.x;
    const int lane = tid & 63;
    const int wv   = tid >> 6;
    const int b0   = blockIdx.x * BPB;

    // Role split with block-parity swap so each SIMD hosts one rec + one gemm
    // wave (instead of two identical heavy waves piling on one SIMD).
    const int  swapr = (int)(blockIdx.x & 1u);
    const bool isRec = swapr ? (wv >= 2) : (wv < 2);
    const int  rw    = swapr ? (wv - 2) : wv;       // rec wave id  0..1
    const int  gw    = swapr ? wv       : (wv - 2); // gemm wave id 0..1

    // ---------- recurrence lane mapping (2 batches per rec wave) ----------
    const int j = lane % NH;
    int wbL = lane / NH; if (wbL > 1) wbL = 1;      // lanes 40..63 duplicate batch 1
    const int base = wbL * NH;

    float4 wi0,wi1,wi2,wi3,wi4, wf0,wf1,wf2,wf3,wf4,
           wg0,wg1,wg2,wg3,wg4, wo0,wo1,wo2,wo3,wo4;
    float bias_i=0.f, bias_f=0.f, bias_g=0.f, bias_o=0.f;
    float ht=0.f, creg=0.f, accum=0.f;

    // ---------- gemm state: lane = output row (batchLocal*16 + t) ----------
    float4 xr[16];                      // this lane's x row for current chunk
    const float* wbase = W_ih;
    const float* xrow  = x;

    // GEMM body for chunk m: p_s[m&1][lane][c0+ c] = dot(W_ih[c0+c], x_row),
    // W via wave-uniform s_load (SGPR operand FMAs), then prefetch chunk m+1.
    auto gbody = [&](int m) {
        float* prow = &p_s[m & 1][lane][0] + (gw * 40);
        #pragma unroll 1
        for (int g = 0; g < 8; ++g) {
            const float* wr = wbase + (size_t)(5 * g) * NF;
            float a0=0.f, a1=0.f, a2=0.f, a3=0.f, a4=0.f;
            #pragma unroll
            for (int k4 = 0; k4 < 16; ++k4) {
                const float4 xv = xr[k4];
                const float4 w0 = *(const float4*)(wr + 0*NF + 4*k4);
                const float4 w1 = *(const float4*)(wr + 1*NF + 4*k4);
                const float4 w2 = *(const float4*)(wr + 2*NF + 4*k4);
                const float4 w3 = *(const float4*)(wr + 3*NF + 4*k4);
                const float4 w4 = *(const float4*)(wr + 4*NF + 4*k4);
                GFMA(a0, w0) GFMA(a1, w1) GFMA(a2, w2) GFMA(a3, w3) GFMA(a4, w4)
            }
            prow[5*g+0] = a0; prow[5*g+1] = a1; prow[5*g+2] = a2;
            prow[5*g+3] = a3; prow[5*g+4] = a4;
        }
        if (m + 1 < NCHUNK) {           // prefetch next chunk's x row (regs now dead)
            const float* xp = xrow + (size_t)(m + 1) * TC * NF;
            #pragma unroll
            for (int k4 = 0; k4 < 16; ++k4)
                xr[k4] = *(const float4*)(xp + 4*k4);
        }
    };

    // ---------------- prologue ----------------
    if (isRec) {
        const float* r0 = W_hh + (size_t)(j)        * NH;
        const float* r1 = W_hh + (size_t)(NH   + j) * NH;
        const float* r2 = W_hh + (size_t)(2*NH + j) * NH;
        const float* r3 = W_hh + (size_t)(3*NH + j) * NH;
        wi0 = *(const float4*)(r0 + 0);  wi1 = *(const float4*)(r0 + 4);
        wi2 = *(const float4*)(r0 + 8);  wi3 = *(const float4*)(r0 + 12);
        wi4 = *(const float4*)(r0 + 16);
        wf0 = *(const float4*)(r1 + 0);  wf1 = *(const float4*)(r1 + 4);
        wf2 = *(const float4*)(r1 + 8);  wf3 = *(const float4*)(r1 + 12);
        wf4 = *(const float4*)(r1 + 16);
        wg0 = *(const float4*)(r2 + 0);  wg1 = *(const float4*)(r2 + 4);
        wg2 = *(const float4*)(r2 + 8);  wg3 = *(const float4*)(r2 + 12);
        wg4 = *(const float4*)(r2 + 16);
        wo0 = *(const float4*)(r3 + 0);  wo1 = *(const float4*)(r3 + 4);
        wo2 = *(const float4*)(r3 + 8);  wo3 = *(const float4*)(r3 + 12);
        wo4 = *(const float4*)(r3 + 16);
        OPAQ4(wi0); OPAQ4(wi1); OPAQ4(wi2); OPAQ4(wi3); OPAQ4(wi4);
        OPAQ4(wf0); OPAQ4(wf1); OPAQ4(wf2); OPAQ4(wf3); OPAQ4(wf4);
        OPAQ4(wg0); OPAQ4(wg1); OPAQ4(wg2); OPAQ4(wg3); OPAQ4(wg4);
        OPAQ4(wo0); OPAQ4(wo1); OPAQ4(wo2); OPAQ4(wo3); OPAQ4(wo4);
        bias_i = b_ih[j]        + b_hh[j];
        bias_f = b_ih[NH + j]   + b_hh[NH + j];
        bias_g = b_ih[2*NH + j] + b_hh[2*NH + j];
        bias_o = b_ih[3*NH + j] + b_hh[3*NH + j];
    } else {
        const int c0 = __builtin_amdgcn_readfirstlane(gw * 40); // wave-uniform -> SGPR
        wbase = W_ih + (size_t)c0 * NF;
        xrow  = x + ((size_t)(b0 + (lane >> 4)) * NT + (lane & 15)) * NF;
        #pragma unroll
        for (int k4 = 0; k4 < 16; ++k4)
            xr[k4] = *(const float4*)(xrow + 4*k4);
        gbody(0);                        // p_s[0] + prefetch chunk 1
    }
    __syncthreads();

    // ---------------- main pipeline: 32 rounds ----------------
    for (int c = 0; c < NCHUNK; ++c) {
        if (isRec) {
            const float* pc  = &p_s[c & 1][(rw * 2 + wbL) * TC][0];
            const float* wlp = W_lin + c * TC * NH + j;
            TSTEP(0)  TSTEP(1)  TSTEP(2)  TSTEP(3)
            TSTEP(4)  TSTEP(5)  TSTEP(6)  TSTEP(7)
            TSTEP(8)  TSTEP(9)  TSTEP(10) TSTEP(11)
            TSTEP(12) TSTEP(13) TSTEP(14) TSTEP(15)
        } else {
            if (c + 1 < NCHUNK) gbody(c + 1);
        }
        __syncthreads();
    }

    // ---------------- epilogue: out[b] = sum_j accum + b_lin ----------------
    if (isRec) {
        float tot = 0.f;
        #pragma unroll
        for (int k = 0; k < NH; ++k) tot += __shfl(accum, base + k, 64);
        if (j == 0 && lane < 2 * NH)
            out[b0 + rw * 2 + wbL] = tot + b_lin[0];
    }
}

extern "C" void kernel_launch(void* const* d_in, const int* in_sizes, int n_in,
                              void* d_out, int out_size, void* d_ws, size_t ws_size,
                              hipStream_t stream) {
    const float* x     = (const float*)d_in[0];
    const float* W_ih  = (const float*)d_in[1];
    const float* W_hh  = (const float*)d_in[2];
    const float* b_ih  = (const float*)d_in[3];
    const float* b_hh  = (const float*)d_in[4];
    const float* W_lin = (const float*)d_in[5];
    const float* b_lin = (const float*)d_in[6];
    float* outp = (float*)d_out;
    mv_lstm_fused<<<NBLK, 256, 0, stream>>>(x, W_ih, W_hh, b_ih, b_hh, W_lin, b_lin, outp);
}

// Round 2
// 1980.185 us; speedup vs baseline: 1.0089x; 1.0089x over previous
//
#include <hip/hip_runtime.h>

#define NB 2048
#define NT 512
#define NF 64
#define NH 20
#define NG 80
#define TC 16
#define NCHUNK (NT/TC)   // 32
#define BPB 4
#define NBLK (NB/BPB)    // 512 blocks = exactly 2 per CU
#define PSTR 85          // p_s row stride: odd -> conflict-free column access

__device__ __forceinline__ float sigm(float v)   { return 1.0f / (1.0f + __expf(-v)); }
__device__ __forceinline__ float tanh_f(float v) { return 1.0f - 2.0f / (1.0f + __expf(2.0f * v)); }

// Opaque register barrier: pin value in VGPRs, stop rematerialization.
#define OPAQ4(v) asm volatile("" : "+v"(v.x), "+v"(v.y), "+v"(v.z), "+v"(v.w))

// ---------------- recurrence: 4 h-broadcasts + 16 FMAs per K4 ----------------
#define K4(VWI, VWF, VWG, VWO, KB)                                            \
    {                                                                         \
        float hk0 = __shfl(ht, base + (KB) + 0, 64);                          \
        float hk1 = __shfl(ht, base + (KB) + 1, 64);                          \
        float hk2 = __shfl(ht, base + (KB) + 2, 64);                          \
        float hk3 = __shfl(ht, base + (KB) + 3, 64);                          \
        s0a = fmaf(VWI.x, hk0, s0a); s0b = fmaf(VWI.y, hk1, s0b);             \
        s0a = fmaf(VWI.z, hk2, s0a); s0b = fmaf(VWI.w, hk3, s0b);             \
        s1a = fmaf(VWF.x, hk0, s1a); s1b = fmaf(VWF.y, hk1, s1b);             \
        s1a = fmaf(VWF.z, hk2, s1a); s1b = fmaf(VWF.w, hk3, s1b);             \
        s2a = fmaf(VWG.x, hk0, s2a); s2b = fmaf(VWG.y, hk1, s2b);             \
        s2a = fmaf(VWG.z, hk2, s2a); s2b = fmaf(VWG.w, hk3, s2b);             \
        s3a = fmaf(VWO.x, hk0, s3a); s3b = fmaf(VWO.y, hk1, s3b);             \
        s3a = fmaf(VWO.z, hk2, s3a); s3b = fmaf(VWO.w, hk3, s3b);             \
    }

#define TSTEP(TL)                                                             \
    {                                                                         \
        const float* pr = pc + (TL) * PSTR;                                   \
        float s0a = pr[j]      + bias_i, s0b = 0.f;                           \
        float s1a = pr[j + 20] + bias_f, s1b = 0.f;                           \
        float s2a = pr[j + 40] + bias_g, s2b = 0.f;                           \
        float s3a = pr[j + 60] + bias_o, s3b = 0.f;                           \
        K4(wi0, wf0, wg0, wo0, 0)  K4(wi1, wf1, wg1, wo1, 4)                  \
        K4(wi2, wf2, wg2, wo2, 8)  K4(wi3, wf3, wg3, wo3, 12)                 \
        K4(wi4, wf4, wg4, wo4, 16)                                            \
        float gi = sigm(s0a + s0b);                                           \
        float gf = sigm(s1a + s1b);                                           \
        float gg = tanh_f(s2a + s2b);                                         \
        float go = sigm(s3a + s3b);                                           \
        creg = gf * creg + gi * gg;                                           \
        ht   = go * tanh_f(creg);                                             \
        accum = fmaf(ht, wlp[(TL) * NH], accum);                              \
    }

// ---------------- GEMM: all-register, macro-unrolled (NO arrays/lambdas) -----
#define GFMA(AV, WV) { AV = fmaf(xv.x, WV.x, AV); AV = fmaf(xv.y, WV.y, AV);  \
                       AV = fmaf(xv.z, WV.z, AV); AV = fmaf(xv.w, WV.w, AV); }

#define GK(K)                                                                 \
    {                                                                         \
        const float4 xv  = x##K;                                              \
        const float4 w0v = *(const float4*)(wr + 0*NF + 4*(K));               \
        const float4 w1v = *(const float4*)(wr + 1*NF + 4*(K));               \
        const float4 w2v = *(const float4*)(wr + 2*NF + 4*(K));               \
        const float4 w3v = *(const float4*)(wr + 3*NF + 4*(K));               \
        const float4 w4v = *(const float4*)(wr + 4*NF + 4*(K));               \
        GFMA(a0, w0v) GFMA(a1, w1v) GFMA(a2, w2v) GFMA(a3, w3v) GFMA(a4, w4v) \
    }

#define GBODY(mm)                                                             \
    {                                                                         \
        float* prow = &p_s[(mm) & 1][lane][0] + gw40;                         \
        _Pragma("unroll 1")                                                   \
        for (int g = 0; g < 8; ++g) {                                         \
            const float* wr = wbase + (size_t)(5 * g) * NF;                   \
            float a0=0.f, a1=0.f, a2=0.f, a3=0.f, a4=0.f;                     \
            GK(0)  GK(1)  GK(2)  GK(3)  GK(4)  GK(5)  GK(6)  GK(7)            \
            GK(8)  GK(9)  GK(10) GK(11) GK(12) GK(13) GK(14) GK(15)           \
            prow[0]=a0; prow[1]=a1; prow[2]=a2; prow[3]=a3; prow[4]=a4;       \
            prow += 5;                                                        \
        }                                                                     \
    }

#define XPREF(mm)                                                             \
    {                                                                         \
        const float* xp = xrow + (size_t)(mm) * (TC * NF);                    \
        x0  = *(const float4*)(xp +  0); x1  = *(const float4*)(xp +  4);     \
        x2  = *(const float4*)(xp +  8); x3  = *(const float4*)(xp + 12);     \
        x4  = *(const float4*)(xp + 16); x5  = *(const float4*)(xp + 20);     \
        x6  = *(const float4*)(xp + 24); x7  = *(const float4*)(xp + 28);     \
        x8  = *(const float4*)(xp + 32); x9  = *(const float4*)(xp + 36);     \
        x10 = *(const float4*)(xp + 40); x11 = *(const float4*)(xp + 44);     \
        x12 = *(const float4*)(xp + 48); x13 = *(const float4*)(xp + 52);     \
        x14 = *(const float4*)(xp + 56); x15 = *(const float4*)(xp + 60);     \
    }

__global__ __launch_bounds__(256, 2) void mv_lstm_fused(
    const float* __restrict__ x, const float* __restrict__ W_ih,
    const float* __restrict__ W_hh, const float* __restrict__ b_ih,
    const float* __restrict__ b_hh, const float* __restrict__ W_lin,
    const float* __restrict__ b_lin, float* __restrict__ out)
{
    __shared__ float p_s[2][BPB*TC][PSTR];   // 43.5 KB, the only LDS

    const int tid  = threadIdx.x;
    const int lane = tid & 63;
    const int wv   = tid >> 6;
    const int b0   = blockIdx.x * BPB;

    // Role split with block-parity swap so each SIMD hosts one rec + one gemm wave.
    const int  swapr = (int)(blockIdx.x & 1u);
    const bool isRec = swapr ? (wv >= 2) : (wv < 2);
    const int  rw    = swapr ? (wv - 2) : wv;       // rec wave id  0..1
    const int  gw    = swapr ? wv       : (wv - 2); // gemm wave id 0..1
    const int  gw40  = gw * 40;

    // ---------- recurrence lane mapping (2 batches per rec wave) ----------
    const int j = lane % NH;
    int wbL = lane / NH; if (wbL > 1) wbL = 1;      // lanes 40..63 duplicate batch 1
    const int base = wbL * NH;

    float4 wi0,wi1,wi2,wi3,wi4, wf0,wf1,wf2,wf3,wf4,
           wg0,wg1,wg2,wg3,wg4, wo0,wo1,wo2,wo3,wo4;
    float bias_i=0.f, bias_f=0.f, bias_g=0.f, bias_o=0.f;
    float ht=0.f, creg=0.f, accum=0.f;

    // ---------- gemm state: lane = output row; x row in 16 NAMED float4 regs --
    float4 x0,x1,x2,x3,x4,x5,x6,x7,x8,x9,x10,x11,x12,x13,x14,x15;
    const float* wbase = W_ih + (size_t)gw40 * NF;                 // wave-uniform
    const float* xrow  = x + ((size_t)(b0 + (lane >> 4)) * NT + (lane & 15)) * NF;

    // ---------------- prologue ----------------
    if (isRec) {
        const float* r0 = W_hh + (size_t)(j)        * NH;
        const float* r1 = W_hh + (size_t)(NH   + j) * NH;
        const float* r2 = W_hh + (size_t)(2*NH + j) * NH;
        const float* r3 = W_hh + (size_t)(3*NH + j) * NH;
        wi0 = *(const float4*)(r0 + 0);  wi1 = *(const float4*)(r0 + 4);
        wi2 = *(const float4*)(r0 + 8);  wi3 = *(const float4*)(r0 + 12);
        wi4 = *(const float4*)(r0 + 16);
        wf0 = *(const float4*)(r1 + 0);  wf1 = *(const float4*)(r1 + 4);
        wf2 = *(const float4*)(r1 + 8);  wf3 = *(const float4*)(r1 + 12);
        wf4 = *(const float4*)(r1 + 16);
        wg0 = *(const float4*)(r2 + 0);  wg1 = *(const float4*)(r2 + 4);
        wg2 = *(const float4*)(r2 + 8);  wg3 = *(const float4*)(r2 + 12);
        wg4 = *(const float4*)(r2 + 16);
        wo0 = *(const float4*)(r3 + 0);  wo1 = *(const float4*)(r3 + 4);
        wo2 = *(const float4*)(r3 + 8);  wo3 = *(const float4*)(r3 + 12);
        wo4 = *(const float4*)(r3 + 16);
        OPAQ4(wi0); OPAQ4(wi1); OPAQ4(wi2); OPAQ4(wi3); OPAQ4(wi4);
        OPAQ4(wf0); OPAQ4(wf1); OPAQ4(wf2); OPAQ4(wf3); OPAQ4(wf4);
        OPAQ4(wg0); OPAQ4(wg1); OPAQ4(wg2); OPAQ4(wg3); OPAQ4(wg4);
        OPAQ4(wo0); OPAQ4(wo1); OPAQ4(wo2); OPAQ4(wo3); OPAQ4(wo4);
        bias_i = b_ih[j]        + b_hh[j];
        bias_f = b_ih[NH + j]   + b_hh[NH + j];
        bias_g = b_ih[2*NH + j] + b_hh[2*NH + j];
        bias_o = b_ih[3*NH + j] + b_hh[3*NH + j];
    } else {
        XPREF(0)
        GBODY(0)            // p_s[0] for chunk 0
        XPREF(1)            // prefetch chunk 1 into the (now dead) x regs
    }
    __syncthreads();

    // ---------------- main pipeline: 32 rounds ----------------
    for (int c = 0; c < NCHUNK; ++c) {
        if (isRec) {
            const float* pc  = &p_s[c & 1][(rw * 2 + wbL) * TC][0];
            const float* wlp = W_lin + c * TC * NH + j;
            TSTEP(0)  TSTEP(1)  TSTEP(2)  TSTEP(3)
            TSTEP(4)  TSTEP(5)  TSTEP(6)  TSTEP(7)
            TSTEP(8)  TSTEP(9)  TSTEP(10) TSTEP(11)
            TSTEP(12) TSTEP(13) TSTEP(14) TSTEP(15)
        } else {
            if (c + 1 < NCHUNK) {
                GBODY(c + 1)
                if (c + 2 < NCHUNK) XPREF(c + 2)
            }
        }
        __syncthreads();
    }

    // ---------------- epilogue: out[b] = sum_j accum + b_lin ----------------
    if (isRec) {
        float tot = 0.f;
        #pragma unroll
        for (int k = 0; k < NH; ++k) tot += __shfl(accum, base + k, 64);
        if (j == 0 && lane < 2 * NH)
            out[b0 + rw * 2 + wbL] = tot + b_lin[0];
    }
}

extern "C" void kernel_launch(void* const* d_in, const int* in_sizes, int n_in,
                              void* d_out, int out_size, void* d_ws, size_t ws_size,
                              hipStream_t stream) {
    const float* x     = (const float*)d_in[0];
    const float* W_ih  = (const float*)d_in[1];
    const float* W_hh  = (const float*)d_in[2];
    const float* b_ih  = (const float*)d_in[3];
    const float* b_hh  = (const float*)d_in[4];
    const float* W_lin = (const float*)d_in[5];
    const float* b_lin = (const float*)d_in[6];
    float* outp = (float*)d_out;
    mv_lstm_fused<<<NBLK, 256, 0, stream>>>(x, W_ih, W_hh, b_ih, b_hh, W_lin, b_lin, outp);
}

// Round 3
// 1104.705 us; speedup vs baseline: 1.8085x; 1.7925x over previous
//
#include <hip/hip_runtime.h>

#define NB 2048
#define NT 512
#define NF 64
#define NH 20
#define TC 16
#define NCHUNK (NT/TC)   // 32
#define BPB 4
#define NBLK (NB/BPB)    // 512 blocks = exactly 2 per CU
#define PSTR 85          // p_s row stride: 85 mod 32 = 21 (odd) -> conflict-free cols

__device__ __forceinline__ float sigm(float v)   { return 1.0f / (1.0f + __expf(-v)); }
__device__ __forceinline__ float tanh_f(float v) { return 1.0f - 2.0f / (1.0f + __expf(2.0f * v)); }

// Opaque register barrier: pin value in VGPRs, stop rematerialization.
#define OPAQ4(v) asm volatile("" : "+v"(v.x), "+v"(v.y), "+v"(v.z), "+v"(v.w))

// ---------------- recurrence: 4 h-broadcasts + 16 FMAs per K4 ----------------
// Shared register file r0..r19 (see below):
//   rec waves:  W_i = r0..r4, W_f = r5..r9, W_g = r10..r14, W_o = r15..r19
//   gemm waves: x row k4-block K lives in rK (K = 0..15); r16..r19 unused
#define K4(VWI, VWF, VWG, VWO, KB)                                            \
    {                                                                         \
        float hk0 = __shfl(ht, base + (KB) + 0, 64);                          \
        float hk1 = __shfl(ht, base + (KB) + 1, 64);                          \
        float hk2 = __shfl(ht, base + (KB) + 2, 64);                          \
        float hk3 = __shfl(ht, base + (KB) + 3, 64);                          \
        s0a = fmaf(VWI.x, hk0, s0a); s0b = fmaf(VWI.y, hk1, s0b);             \
        s0a = fmaf(VWI.z, hk2, s0a); s0b = fmaf(VWI.w, hk3, s0b);             \
        s1a = fmaf(VWF.x, hk0, s1a); s1b = fmaf(VWF.y, hk1, s1b);             \
        s1a = fmaf(VWF.z, hk2, s1a); s1b = fmaf(VWF.w, hk3, s1b);             \
        s2a = fmaf(VWG.x, hk0, s2a); s2b = fmaf(VWG.y, hk1, s2b);             \
        s2a = fmaf(VWG.z, hk2, s2a); s2b = fmaf(VWG.w, hk3, s2b);             \
        s3a = fmaf(VWO.x, hk0, s3a); s3b = fmaf(VWO.y, hk1, s3b);             \
        s3a = fmaf(VWO.z, hk2, s3a); s3b = fmaf(VWO.w, hk3, s3b);             \
    }

#define TSTEP(TL)                                                             \
    {                                                                         \
        const float* pr = pc + (TL) * PSTR;                                   \
        float s0a = pr[j]      + bias_i, s0b = 0.f;                           \
        float s1a = pr[j + 20] + bias_f, s1b = 0.f;                           \
        float s2a = pr[j + 40] + bias_g, s2b = 0.f;                           \
        float s3a = pr[j + 60] + bias_o, s3b = 0.f;                           \
        K4(r0, r5, r10, r15, 0)   K4(r1, r6, r11, r16, 4)                     \
        K4(r2, r7, r12, r17, 8)   K4(r3, r8, r13, r18, 12)                    \
        K4(r4, r9, r14, r19, 16)                                              \
        float gi = sigm(s0a + s0b);                                           \
        float gf = sigm(s1a + s1b);                                           \
        float gg = tanh_f(s2a + s2b);                                         \
        float go = sigm(s3a + s3b);                                           \
        creg = gf * creg + gi * gg;                                           \
        ht   = go * tanh_f(creg);                                             \
        accum = fmaf(ht, wlp[(TL) * NH], accum);                              \
    }

// ---------------- GEMM: all-register, macro-unrolled -------------------------
#define GFMA(AV, WV) { AV = fmaf(xv.x, WV.x, AV); AV = fmaf(xv.y, WV.y, AV);  \
                       AV = fmaf(xv.z, WV.z, AV); AV = fmaf(xv.w, WV.w, AV); }

#define GK(K)                                                                 \
    {                                                                         \
        const float4 xv  = r##K;                                              \
        const float4 w0v = *(const float4*)(wr + 0*NF + 4*(K));               \
        const float4 w1v = *(const float4*)(wr + 1*NF + 4*(K));               \
        const float4 w2v = *(const float4*)(wr + 2*NF + 4*(K));               \
        const float4 w3v = *(const float4*)(wr + 3*NF + 4*(K));               \
        const float4 w4v = *(const float4*)(wr + 4*NF + 4*(K));               \
        GFMA(a0, w0v) GFMA(a1, w1v) GFMA(a2, w2v) GFMA(a3, w3v) GFMA(a4, w4v) \
    }

#define GBODY(mm)                                                             \
    {                                                                         \
        float* prow = &p_s[(mm) & 1][lane][0] + gw40;                         \
        _Pragma("unroll 1")                                                   \
        for (int g = 0; g < 8; ++g) {                                         \
            const float* wr = wbase + (size_t)(5 * g) * NF;                   \
            float a0=0.f, a1=0.f, a2=0.f, a3=0.f, a4=0.f;                     \
            GK(0)  GK(1)  GK(2)  GK(3)  GK(4)  GK(5)  GK(6)  GK(7)            \
            GK(8)  GK(9)  GK(10) GK(11) GK(12) GK(13) GK(14) GK(15)           \
            prow[0]=a0; prow[1]=a1; prow[2]=a2; prow[3]=a3; prow[4]=a4;       \
            prow += 5;                                                        \
        }                                                                     \
    }

#define XPREF(mm)                                                             \
    {                                                                         \
        const float* xp = xrow + (size_t)(mm) * (TC * NF);                    \
        r0  = *(const float4*)(xp +  0); r1  = *(const float4*)(xp +  4);     \
        r2  = *(const float4*)(xp +  8); r3  = *(const float4*)(xp + 12);     \
        r4  = *(const float4*)(xp + 16); r5  = *(const float4*)(xp + 20);     \
        r6  = *(const float4*)(xp + 24); r7  = *(const float4*)(xp + 28);     \
        r8  = *(const float4*)(xp + 32); r9  = *(const float4*)(xp + 36);     \
        r10 = *(const float4*)(xp + 40); r11 = *(const float4*)(xp + 44);     \
        r12 = *(const float4*)(xp + 48); r13 = *(const float4*)(xp + 52);     \
        r14 = *(const float4*)(xp + 56); r15 = *(const float4*)(xp + 60);     \
    }

__global__ __launch_bounds__(256, 1) void mv_lstm_fused(
    const float* __restrict__ x, const float* __restrict__ W_ih,
    const float* __restrict__ W_hh, const float* __restrict__ b_ih,
    const float* __restrict__ b_hh, const float* __restrict__ W_lin,
    const float* __restrict__ b_lin, float* __restrict__ out)
{
    __shared__ float p_s[2][BPB*TC][PSTR];   // 43.5 KB, the only LDS

    const int tid  = threadIdx.x;
    const int lane = tid & 63;
    const int wv   = tid >> 6;
    const int b0   = blockIdx.x * BPB;

    // Role split with block-parity swap so each SIMD hosts one rec + one gemm wave.
    const int  swapr = (int)(blockIdx.x & 1u);
    const bool isRec = swapr ? (wv >= 2) : (wv < 2);
    const int  rw    = swapr ? (wv - 2) : wv;       // rec wave id  0..1
    const int  gw    = swapr ? wv       : (wv - 2); // gemm wave id 0..1
    const int  gw40  = gw * 40;

    // ---------- recurrence lane mapping (2 batches per rec wave) ----------
    const int j = lane % NH;
    int wbL = lane / NH; if (wbL > 1) wbL = 1;      // lanes 40..63 duplicate batch 1
    const int base = wbL * NH;

    // ---------- SHARED register file: one set of 20 float4 for BOTH roles ----
    // rec waves hold W_hh here (persistent); gemm waves hold the x row here
    // (rewritten every chunk). Same virtual regs -> no cross-role interference.
    float4 r0  = {0,0,0,0}, r1  = {0,0,0,0}, r2  = {0,0,0,0}, r3  = {0,0,0,0};
    float4 r4  = {0,0,0,0}, r5  = {0,0,0,0}, r6  = {0,0,0,0}, r7  = {0,0,0,0};
    float4 r8  = {0,0,0,0}, r9  = {0,0,0,0}, r10 = {0,0,0,0}, r11 = {0,0,0,0};
    float4 r12 = {0,0,0,0}, r13 = {0,0,0,0}, r14 = {0,0,0,0}, r15 = {0,0,0,0};
    float4 r16 = {0,0,0,0}, r17 = {0,0,0,0}, r18 = {0,0,0,0}, r19 = {0,0,0,0};

    float bias_i=0.f, bias_f=0.f, bias_g=0.f, bias_o=0.f;
    float ht=0.f, creg=0.f, accum=0.f;

    const float* wbase = W_ih + (size_t)gw40 * NF;                 // wave-uniform
    const float* xrow  = x + ((size_t)(b0 + (lane >> 4)) * NT + (lane & 15)) * NF;

    // ---------------- prologue ----------------
    if (isRec) {
        const float* p0 = W_hh + (size_t)(j)        * NH;
        const float* p1 = W_hh + (size_t)(NH   + j) * NH;
        const float* p2 = W_hh + (size_t)(2*NH + j) * NH;
        const float* p3 = W_hh + (size_t)(3*NH + j) * NH;
        r0  = *(const float4*)(p0 + 0);  r1  = *(const float4*)(p0 + 4);
        r2  = *(const float4*)(p0 + 8);  r3  = *(const float4*)(p0 + 12);
        r4  = *(const float4*)(p0 + 16);
        r5  = *(const float4*)(p1 + 0);  r6  = *(const float4*)(p1 + 4);
        r7  = *(const float4*)(p1 + 8);  r8  = *(const float4*)(p1 + 12);
        r9  = *(const float4*)(p1 + 16);
        r10 = *(const float4*)(p2 + 0);  r11 = *(const float4*)(p2 + 4);
        r12 = *(const float4*)(p2 + 8);  r13 = *(const float4*)(p2 + 12);
        r14 = *(const float4*)(p2 + 16);
        r15 = *(const float4*)(p3 + 0);  r16 = *(const float4*)(p3 + 4);
        r17 = *(const float4*)(p3 + 8);  r18 = *(const float4*)(p3 + 12);
        r19 = *(const float4*)(p3 + 16);
        OPAQ4(r0);  OPAQ4(r1);  OPAQ4(r2);  OPAQ4(r3);  OPAQ4(r4);
        OPAQ4(r5);  OPAQ4(r6);  OPAQ4(r7);  OPAQ4(r8);  OPAQ4(r9);
        OPAQ4(r10); OPAQ4(r11); OPAQ4(r12); OPAQ4(r13); OPAQ4(r14);
        OPAQ4(r15); OPAQ4(r16); OPAQ4(r17); OPAQ4(r18); OPAQ4(r19);
        bias_i = b_ih[j]        + b_hh[j];
        bias_f = b_ih[NH + j]   + b_hh[NH + j];
        bias_g = b_ih[2*NH + j] + b_hh[2*NH + j];
        bias_o = b_ih[3*NH + j] + b_hh[3*NH + j];
    } else {
        XPREF(0)
        GBODY(0)            // p_s[0] for chunk 0
        XPREF(1)            // prefetch chunk 1 into the (now dead) x regs
    }
    __syncthreads();

    // ---------------- main pipeline: 32 rounds ----------------
    for (int c = 0; c < NCHUNK; ++c) {
        if (isRec) {
            const float* pc  = &p_s[c & 1][(rw * 2 + wbL) * TC][0];
            const float* wlp = W_lin + c * TC * NH + j;
            TSTEP(0)  TSTEP(1)  TSTEP(2)  TSTEP(3)
            TSTEP(4)  TSTEP(5)  TSTEP(6)  TSTEP(7)
            TSTEP(8)  TSTEP(9)  TSTEP(10) TSTEP(11)
            TSTEP(12) TSTEP(13) TSTEP(14) TSTEP(15)
        } else {
            if (c + 1 < NCHUNK) {
                GBODY(c + 1)
                if (c + 2 < NCHUNK) XPREF(c + 2)
            }
        }
        __syncthreads();
    }

    // ---------------- epilogue: out[b] = sum_j accum + b_lin ----------------
    if (isRec) {
        float tot = 0.f;
        #pragma unroll
        for (int k = 0; k < NH; ++k) tot += __shfl(accum, base + k, 64);
        if (j == 0 && lane < 2 * NH)
            out[b0 + rw * 2 + wbL] = tot + b_lin[0];
    }
}

extern "C" void kernel_launch(void* const* d_in, const int* in_sizes, int n_in,
                              void* d_out, int out_size, void* d_ws, size_t ws_size,
                              hipStream_t stream) {
    const float* x     = (const float*)d_in[0];
    const float* W_ih  = (const float*)d_in[1];
    const float* W_hh  = (const float*)d_in[2];
    const float* b_ih  = (const float*)d_in[3];
    const float* b_hh  = (const float*)d_in[4];
    const float* W_lin = (const float*)d_in[5];
    const float* b_lin = (const float*)d_in[6];
    float* outp = (float*)d_out;
    mv_lstm_fused<<<NBLK, 256, 0, stream>>>(x, W_ih, W_hh, b_ih, b_hh, W_lin, b_lin, outp);
}